// Round 2
// baseline (578.212 us; speedup 1.0000x reference)
//
#include <hip/hip_runtime.h>
#include <math.h>

#define NROWS   8192
#define DHH     64
#define BHCOUNT 64
#define HCOUNT  16
#define SPLITA  16
#define CHUNKA  (NROWS / SPLITA)   // 512
#define GA      32                 // rows per LDS group in phase A
#define LSTR    68                 // padded LDS row stride (floats)
#define SPLITB  32
#define CHUNKB  (NROWS / SPLITB)   // 256
#define CTXSZ   4160               // 64*64 context + 64 v2_sum
#define EPS_DN  1e-5f
#define PROJ_EPS 0.004f
#define NGA     (CHUNKA / GA)      // 16 groups
#define ABUF    (2 * GA * LSTR)    // floats per phaseA buffer (v2s|xs)

__device__ __forceinline__ float elu1(float x) {
    return x > 0.0f ? x + 1.0f : expf(x);   // elu(x)+1
}
__device__ __forceinline__ float rlane(float v, int l) {
    return __uint_as_float(__builtin_amdgcn_readlane(__float_as_uint(v), l));
}

// ---------------- Phase A: per-row v2/x, accumulate context & v2_sum ----------------
// 8x8 register tile per lane (full 64x64 per wave, rows r==wave mod 4).
// Double-buffered LDS (ONE barrier per group) + register prefetch of next group's
// K/V so global latency hides under the ~1024-cyc acc loop.
__global__ __launch_bounds__(256, 4) void phaseA(
        const float* __restrict__ Kp, const float* __restrict__ Vp,
        const float* __restrict__ maskp, const float* __restrict__ curvp,
        float* __restrict__ denomWs, float* __restrict__ partials) {
    __shared__ __align__(16) float smem[2 * ABUF];   // 2 x (v2s|xs) = 34816 B
    const int bx = blockIdx.x;
    const int bh = bx / SPLITA, sp = bx % SPLITA;
    const float k = curvp[bh % HCOUNT];
    const int t = threadIdx.x;
    const int rowBase = sp * CHUNKA;
    const float* Kb = Kp + (size_t)bh * NROWS * DHH;
    const float* Vb = Vp + (size_t)bh * NROWS * DHH;

    const int wave = t >> 6;
    const int lane = t & 63;
    const int d0 = (lane >> 3) * 8;   // context row block (from v2)
    const int e0 = (lane & 7) * 8;    // context col block (from x)
    const int rloc = t >> 4;          // staging row within half-group
    const int c4   = t & 15;          // staging column group of 4

    float acc[8][8];
    #pragma unroll
    for (int i = 0; i < 8; ++i)
        #pragma unroll
        for (int j = 0; j < 8; ++j) acc[i][j] = 0.f;
    float4 v2sum4 = make_float4(0.f, 0.f, 0.f, 0.f);

    // prologue: load group 0 into registers
    float4 pV[2], pK[2];
    #pragma unroll
    for (int pass = 0; pass < 2; ++pass) {
        const int n = rowBase + pass * 16 + rloc;
        pV[pass] = *(const float4*)(Vb + (size_t)n * DHH + 4 * c4);
        pK[pass] = *(const float4*)(Kb + (size_t)n * DHH + 4 * c4);
    }

    for (int g = 0; g < NGA; ++g) {
        // ---- issue next group's loads early (in flight during compute+acc) ----
        float4 nV[2], nK[2];
        if (g + 1 < NGA) {
            #pragma unroll
            for (int pass = 0; pass < 2; ++pass) {
                const int n = rowBase + (g + 1) * GA + pass * 16 + rloc;
                nV[pass] = *(const float4*)(Vb + (size_t)n * DHH + 4 * c4);
                nK[pass] = *(const float4*)(Kb + (size_t)n * DHH + 4 * c4);
            }
        }
        float* v2s = smem + (g & 1) * ABUF;
        float* xs  = v2s + GA * LSTR;
        // ---- process current group's registers -> LDS ----
        #pragma unroll
        for (int pass = 0; pass < 2; ++pass) {
            const int rl = pass * 16 + rloc;
            const int n = rowBase + g * GA + rl;
            const float4 v4 = pV[pass];
            const float4 k4 = pK[pass];
            float ss = v4.x*v4.x + v4.y*v4.y + v4.z*v4.z + v4.w*v4.w;
            ss += __shfl_xor(ss, 1);
            ss += __shfl_xor(ss, 2);
            ss += __shfl_xor(ss, 4);
            ss += __shfl_xor(ss, 8);
            const float dv    = fmaxf(1.0f + k * ss, 1e-15f);
            const float gamma = 2.0f / dv;
            const float gm1   = gamma - 1.0f;
            const float dnm   = (gm1 >= 0.0f ? 1.0f : -1.0f) * fmaxf(fabsf(gm1), 1e-10f);
            const float m     = maskp[n];
            const float idv   = 1.0f / dv;
            const float cv2   = dnm * m;
            const float cx    = (gamma / dnm) * m;
            float4 v2v, xv;
            v2v.x = cv2 * elu1(k4.x * idv);
            v2v.y = cv2 * elu1(k4.y * idv);
            v2v.z = cv2 * elu1(k4.z * idv);
            v2v.w = cv2 * elu1(k4.w * idv);
            xv.x = cx * v4.x; xv.y = cx * v4.y; xv.z = cx * v4.z; xv.w = cx * v4.w;
            *(float4*)&v2s[rl * LSTR + 4 * c4] = v2v;
            *(float4*)&xs [rl * LSTR + 4 * c4] = xv;
            v2sum4.x += v2v.x; v2sum4.y += v2v.y; v2sum4.z += v2v.z; v2sum4.w += v2v.w;
            if (c4 == 0) denomWs[(size_t)bh * NROWS + n] = dv;
        }
        __syncthreads();   // single barrier per group (double-buffered)
        // ---- accumulate 64x64 context over this wave's rows ----
        #pragma unroll 2
        for (int r = wave; r < GA; r += 4) {
            const float4 alo = *(const float4*)&v2s[r * LSTR + d0];
            const float4 ahi = *(const float4*)&v2s[r * LSTR + d0 + 4];
            const float4 blo = *(const float4*)&xs [r * LSTR + e0];
            const float4 bhi = *(const float4*)&xs [r * LSTR + e0 + 4];
            const float af[8] = {alo.x, alo.y, alo.z, alo.w, ahi.x, ahi.y, ahi.z, ahi.w};
            const float bf[8] = {blo.x, blo.y, blo.z, blo.w, bhi.x, bhi.y, bhi.z, bhi.w};
            #pragma unroll
            for (int i = 0; i < 8; ++i)
                #pragma unroll
                for (int j = 0; j < 8; ++j)
                    acc[i][j] += af[i] * bf[j];
        }
        pV[0] = nV[0]; pV[1] = nV[1]; pK[0] = nK[0]; pK[1] = nK[1];
    }
    __syncthreads();

    // ---- cross-wave reduction of the 64x64 context into smem[0..4095] ----
    float* red = smem;   // disjoint from last-used buffer (buf1 at offset ABUF)
    for (int w = 0; w < 4; ++w) {
        if (wave == w) {
            #pragma unroll
            for (int i = 0; i < 8; ++i) {
                const int base = (d0 + i) * DHH + e0;
                float4 lo = make_float4(acc[i][0], acc[i][1], acc[i][2], acc[i][3]);
                float4 hi = make_float4(acc[i][4], acc[i][5], acc[i][6], acc[i][7]);
                if (w != 0) {
                    const float4 plo = *(const float4*)&red[base];
                    const float4 phi = *(const float4*)&red[base + 4];
                    lo.x += plo.x; lo.y += plo.y; lo.z += plo.z; lo.w += plo.w;
                    hi.x += phi.x; hi.y += phi.y; hi.z += phi.z; hi.w += phi.w;
                }
                *(float4*)&red[base]     = lo;
                *(float4*)&red[base + 4] = hi;
            }
        }
        __syncthreads();
    }

    // ---- write partial context (4096 floats, 16 per thread) ----
    float* pbase = partials + (size_t)(bh * SPLITA + sp) * CTXSZ;
    #pragma unroll
    for (int i = 0; i < 4; ++i) {
        const int idx = t * 16 + i * 4;
        *(float4*)(pbase + idx) = *(const float4*)&red[idx];
    }
    // ---- reduce v2_sum across threads (reuse smem as scratch) ----
    __syncthreads();
    *(float4*)&smem[t * 4] = v2sum4;
    __syncthreads();
    if (t < DHH) {
        const int cc = t >> 2, j = t & 3;
        float s = 0.f;
        #pragma unroll
        for (int q = 0; q < 16; ++q) s += smem[(q * 16 + cc) * 4 + j];
        pbase[4096 + t] = s;
    }
}

// ---------------- Reduce partials across SPLITA (1024 blocks) ----------------
#define RSEG 16   // CTXSZ / RSEG = 260 elements per block
__global__ __launch_bounds__(256) void reduceCtx(
        const float* __restrict__ partials, float* __restrict__ ctxsum) {
    const int bh  = blockIdx.x / RSEG;
    const int seg = blockIdx.x % RSEG;
    const int t = threadIdx.x;
    const int base = seg * 260;
    for (int i = t; i < 260; i += 256) {
        const int idx = base + i;
        const float* p = partials + (size_t)bh * SPLITA * CTXSZ + idx;
        float s = 0.f;
        #pragma unroll
        for (int sp = 0; sp < SPLITA; ++sp) s += p[(size_t)sp * CTXSZ];
        ctxsum[(size_t)bh * CTXSZ + idx] = s;
    }
}

// ---------------- Phase B: X = D_inv * v1 @ context, project/mobius/project ----------------
// No LDS, no barriers. ctx column `lane` lives in 64 VGPRs per lane; v1 loaded
// lane=d (coalesced); broadcasts via v_readlane -> SGPR feeding v_fmac.
// Mobius half-angle in closed form (no tanh/atanh).
__global__ __launch_bounds__(256, 4) void phaseB(
        const float* __restrict__ Qp, const float* __restrict__ curvp,
        const float* __restrict__ denomWs, const float* __restrict__ ctxsum,
        float* __restrict__ outp) {
    const int bx = blockIdx.x;
    const int bh = bx / SPLITB, sp = bx % SPLITB;
    const float k = curvp[bh % HCOUNT];
    const float sk = sqrtf(fabsf(k) + 1e-15f);
    const float maxnorm = (k < 0.0f) ? (1.0f - PROJ_EPS) / sk : 1e15f;
    const int t = threadIdx.x;
    const int wave = t >> 6;
    const int lane = t & 63;

    // ---- ctx column `lane` into 64 registers; v2_sum element `lane` ----
    const float* cb = ctxsum + (size_t)bh * CTXSZ;
    float ctxr[DHH];
    #pragma unroll
    for (int d = 0; d < DHH; ++d) ctxr[d] = cb[d * DHH + lane];
    const float v2s = cb[4096 + lane];

    const float* Qb  = Qp   + (size_t)bh * NROWS * DHH;
    float*       Ob  = outp + (size_t)bh * NROWS * DHH;
    const float* dvb = denomWs + (size_t)bh * NROWS;
    const int n0 = sp * CHUNKB + wave * 64;   // this wave's 64 rows
    const int lm = lane & 3;

    // prologue: group 0 loads (4 rows, lane=d layout)
    float qc0 = Qb[(size_t)(n0 + 0) * DHH + lane];
    float qc1 = Qb[(size_t)(n0 + 1) * DHH + lane];
    float qc2 = Qb[(size_t)(n0 + 2) * DHH + lane];
    float qc3 = Qb[(size_t)(n0 + 3) * DHH + lane];
    float dc0 = dvb[n0 + 0], dc1 = dvb[n0 + 1], dc2 = dvb[n0 + 2], dc3 = dvb[n0 + 3];

    #pragma unroll 1
    for (int g = 0; g < 16; ++g) {
        const int nb = n0 + g * 4;
        // ---- prefetch next group ----
        float qn0, qn1, qn2, qn3, dn0, dn1, dn2, dn3;
        if (g < 15) {
            qn0 = Qb[(size_t)(nb + 4) * DHH + lane];
            qn1 = Qb[(size_t)(nb + 5) * DHH + lane];
            qn2 = Qb[(size_t)(nb + 6) * DHH + lane];
            qn3 = Qb[(size_t)(nb + 7) * DHH + lane];
            dn0 = dvb[nb + 4]; dn1 = dvb[nb + 5]; dn2 = dvb[nb + 6]; dn3 = dvb[nb + 7];
        }
        // ---- v1 = elu(Q/dv)+1 (lane = d) ----
        const float v10 = elu1(qc0 * (1.0f / dc0));
        const float v11 = elu1(qc1 * (1.0f / dc1));
        const float v12 = elu1(qc2 * (1.0f / dc2));
        const float v13 = elu1(qc3 * (1.0f / dc3));
        // ---- Dn_i = sum_d v1_i[d]*v2sum[d]: packed quad-transpose butterfly ----
        float t0 = v10 * v2s, t1 = v11 * v2s, t2 = v12 * v2s, t3 = v13 * v2s;
        t0 += __shfl_xor(t0, 1); t1 += __shfl_xor(t1, 1);
        t2 += __shfl_xor(t2, 1); t3 += __shfl_xor(t3, 1);
        t0 += __shfl_xor(t0, 2); t1 += __shfl_xor(t1, 2);
        t2 += __shfl_xor(t2, 2); t3 += __shfl_xor(t3, 2);
        float p = (lm == 0) ? t0 : (lm == 1) ? t1 : (lm == 2) ? t2 : t3;
        p += __shfl_xor(p, 4); p += __shfl_xor(p, 8);
        p += __shfl_xor(p, 16); p += __shfl_xor(p, 32);
        p = (p == 0.0f) ? EPS_DN : p;
        const float pinv = 1.0f / p;                 // lane holds D_inv for row lm
        const float di0 = rlane(pinv, 0), di1 = rlane(pinv, 1);
        const float di2 = rlane(pinv, 2), di3 = rlane(pinv, 3);
        // ---- GEMM: out[i][lane] = sum_d v1_i[d] * ctx[d][lane] via readlane ----
        float a0 = 0.f, a1 = 0.f, a2 = 0.f, a3 = 0.f;
        #pragma unroll
        for (int d = 0; d < DHH; ++d) {
            a0 = fmaf(rlane(v10, d), ctxr[d], a0);
            a1 = fmaf(rlane(v11, d), ctxr[d], a1);
            a2 = fmaf(rlane(v12, d), ctxr[d], a2);
            a3 = fmaf(rlane(v13, d), ctxr[d], a3);
        }
        a0 *= di0; a1 *= di1; a2 *= di2; a3 *= di3;
        // ---- row sumsq (same packed butterfly) ----
        float u0 = a0 * a0, u1 = a1 * a1, u2 = a2 * a2, u3 = a3 * a3;
        u0 += __shfl_xor(u0, 1); u1 += __shfl_xor(u1, 1);
        u2 += __shfl_xor(u2, 1); u3 += __shfl_xor(u3, 1);
        u0 += __shfl_xor(u0, 2); u1 += __shfl_xor(u1, 2);
        u2 += __shfl_xor(u2, 2); u3 += __shfl_xor(u3, 2);
        float s = (lm == 0) ? u0 : (lm == 1) ? u1 : (lm == 2) ? u2 : u3;
        s += __shfl_xor(s, 4); s += __shfl_xor(s, 8);
        s += __shfl_xor(s, 16); s += __shfl_xor(s, 32);   // lane: sumsq of row lm
        // ---- project -> mobius(0.5) closed form -> project, one factor ----
        const float norm = fmaxf(sqrtf(s), 1e-15f);
        const float f1 = (norm > maxnorm) ? (maxnorm / norm) : 1.0f;
        const float xnorm = fmaxf(norm * f1, 1e-15f);
        const float su = sk * xnorm;
        float tk;
        if (k < 0.0f) {
            const float suc = fminf(su, 1.0f - 1e-7f);
            tk = suc / (1.0f + sqrtf(fmaxf(1.0f - suc * suc, 0.0f)));   // tanh(atanh/2)
        } else {
            tk = su / (1.0f + sqrtf(1.0f + su * su));                   // tan(atan/2)
        }
        tk /= sk;
        const float f2 = tk / xnorm;
        const float n3 = fmaxf(fabsf(tk), 1e-15f);
        const float f3 = (n3 > maxnorm) ? (maxnorm / n3) : 1.0f;
        const float fac = f1 * f2 * f3;               // lane: factor for row lm
        const float f0_ = rlane(fac, 0), f1_ = rlane(fac, 1);
        const float f2_ = rlane(fac, 2), f3_ = rlane(fac, 3);
        // ---- coalesced stores (256B per row) ----
        Ob[(size_t)(nb + 0) * DHH + lane] = a0 * f0_;
        Ob[(size_t)(nb + 1) * DHH + lane] = a1 * f1_;
        Ob[(size_t)(nb + 2) * DHH + lane] = a2 * f2_;
        Ob[(size_t)(nb + 3) * DHH + lane] = a3 * f3_;
        qc0 = qn0; qc1 = qn1; qc2 = qn2; qc3 = qn3;
        dc0 = dn0; dc1 = dn1; dc2 = dn2; dc3 = dn3;
    }
}

extern "C" void kernel_launch(void* const* d_in, const int* in_sizes, int n_in,
                              void* d_out, int out_size, void* d_ws, size_t ws_size,
                              hipStream_t stream) {
    const float* Q    = (const float*)d_in[0];
    const float* K    = (const float*)d_in[1];
    const float* V    = (const float*)d_in[2];
    const float* mask = (const float*)d_in[3];
    const float* curv = (const float*)d_in[4];
    float* out = (float*)d_out;

    float* denomWs  = (float*)d_ws;                                   // 64*8192 floats
    float* partials = denomWs + (size_t)BHCOUNT * NROWS;              // 64*16*4160 floats
    float* ctxsum   = partials + (size_t)BHCOUNT * SPLITA * CTXSZ;    // 64*4160 floats

    phaseA<<<dim3(BHCOUNT * SPLITA), dim3(256), 0, stream>>>(K, V, mask, curv, denomWs, partials);
    reduceCtx<<<dim3(BHCOUNT * RSEG), dim3(256), 0, stream>>>(partials, ctxsum);
    phaseB<<<dim3(BHCOUNT * SPLITB), dim3(256), 0, stream>>>(Q, curv, denomWs, ctxsum, out);
}

// Round 3
// 514.300 us; speedup vs baseline: 1.1243x; 1.1243x over previous
//
#include <hip/hip_runtime.h>
#include <math.h>

#define NROWS   8192
#define DHH     64
#define BHCOUNT 64
#define HCOUNT  16
#define SPLITA  16
#define CHUNKA  (NROWS / SPLITA)   // 512
#define GA      32                 // rows per LDS group in phase A
#define LSTR    68                 // padded LDS row stride (floats), phase A
#define SPLITB  32
#define CHUNKB  (NROWS / SPLITB)   // 256
#define CTXSZ   4160               // 64*64 context + 64 v2_sum
#define EPS_DN  1e-5f
#define PROJ_EPS 0.004f
#define NGA     (CHUNKA / GA)      // 16 groups
#define ABUF    (2 * GA * LSTR)    // floats per phaseA buffer (v2s|xs)

__device__ __forceinline__ float elu1(float x) {
    return x > 0.0f ? x + 1.0f : expf(x);   // elu(x)+1
}

// ---------------- Phase A: per-row v2/x, accumulate context & v2_sum ----------------
// 8x8 register tile per lane (full 64x64 per wave, rows r==wave mod 4).
// Double-buffered LDS (ONE barrier per group) + register prefetch of next group's K/V.
__global__ __launch_bounds__(256) void phaseA(
        const float* __restrict__ Kp, const float* __restrict__ Vp,
        const float* __restrict__ maskp, const float* __restrict__ curvp,
        float* __restrict__ denomWs, float* __restrict__ partials) {
    __shared__ __align__(16) float smem[2 * ABUF];   // 2 x (v2s|xs) = 34816 B
    const int bx = blockIdx.x;
    const int bh = bx / SPLITA, sp = bx % SPLITA;
    const float k = curvp[bh % HCOUNT];
    const int t = threadIdx.x;
    const int rowBase = sp * CHUNKA;
    const float* Kb = Kp + (size_t)bh * NROWS * DHH;
    const float* Vb = Vp + (size_t)bh * NROWS * DHH;

    const int wave = t >> 6;
    const int lane = t & 63;
    const int d0 = (lane >> 3) * 8;   // context row block (from v2)
    const int e0 = (lane & 7) * 8;    // context col block (from x)
    const int rloc = t >> 4;          // staging row within half-group
    const int c4   = t & 15;          // staging column group of 4

    float acc[8][8];
    #pragma unroll
    for (int i = 0; i < 8; ++i)
        #pragma unroll
        for (int j = 0; j < 8; ++j) acc[i][j] = 0.f;
    float4 v2sum4 = make_float4(0.f, 0.f, 0.f, 0.f);

    // prologue: load group 0 into registers
    float4 pV[2], pK[2];
    #pragma unroll
    for (int pass = 0; pass < 2; ++pass) {
        const int n = rowBase + pass * 16 + rloc;
        pV[pass] = *(const float4*)(Vb + (size_t)n * DHH + 4 * c4);
        pK[pass] = *(const float4*)(Kb + (size_t)n * DHH + 4 * c4);
    }

    for (int g = 0; g < NGA; ++g) {
        // ---- issue next group's loads early (in flight during compute+acc) ----
        float4 nV[2], nK[2];
        if (g + 1 < NGA) {
            #pragma unroll
            for (int pass = 0; pass < 2; ++pass) {
                const int n = rowBase + (g + 1) * GA + pass * 16 + rloc;
                nV[pass] = *(const float4*)(Vb + (size_t)n * DHH + 4 * c4);
                nK[pass] = *(const float4*)(Kb + (size_t)n * DHH + 4 * c4);
            }
        }
        float* v2s = smem + (g & 1) * ABUF;
        float* xs  = v2s + GA * LSTR;
        // ---- process current group's registers -> LDS ----
        #pragma unroll
        for (int pass = 0; pass < 2; ++pass) {
            const int rl = pass * 16 + rloc;
            const int n = rowBase + g * GA + rl;
            const float4 v4 = pV[pass];
            const float4 k4 = pK[pass];
            float ss = v4.x*v4.x + v4.y*v4.y + v4.z*v4.z + v4.w*v4.w;
            ss += __shfl_xor(ss, 1);
            ss += __shfl_xor(ss, 2);
            ss += __shfl_xor(ss, 4);
            ss += __shfl_xor(ss, 8);
            const float dv    = fmaxf(1.0f + k * ss, 1e-15f);
            const float gamma = 2.0f / dv;
            const float gm1   = gamma - 1.0f;
            const float dnm   = (gm1 >= 0.0f ? 1.0f : -1.0f) * fmaxf(fabsf(gm1), 1e-10f);
            const float m     = maskp[n];
            const float idv   = 1.0f / dv;
            const float cv2   = dnm * m;
            const float cx    = (gamma / dnm) * m;
            float4 v2v, xv;
            v2v.x = cv2 * elu1(k4.x * idv);
            v2v.y = cv2 * elu1(k4.y * idv);
            v2v.z = cv2 * elu1(k4.z * idv);
            v2v.w = cv2 * elu1(k4.w * idv);
            xv.x = cx * v4.x; xv.y = cx * v4.y; xv.z = cx * v4.z; xv.w = cx * v4.w;
            *(float4*)&v2s[rl * LSTR + 4 * c4] = v2v;
            *(float4*)&xs [rl * LSTR + 4 * c4] = xv;
            v2sum4.x += v2v.x; v2sum4.y += v2v.y; v2sum4.z += v2v.z; v2sum4.w += v2v.w;
            if (c4 == 0) denomWs[(size_t)bh * NROWS + n] = dv;
        }
        __syncthreads();   // single barrier per group (double-buffered)
        // ---- accumulate 64x64 context over this wave's rows ----
        #pragma unroll 2
        for (int r = wave; r < GA; r += 4) {
            const float4 alo = *(const float4*)&v2s[r * LSTR + d0];
            const float4 ahi = *(const float4*)&v2s[r * LSTR + d0 + 4];
            const float4 blo = *(const float4*)&xs [r * LSTR + e0];
            const float4 bhi = *(const float4*)&xs [r * LSTR + e0 + 4];
            const float af[8] = {alo.x, alo.y, alo.z, alo.w, ahi.x, ahi.y, ahi.z, ahi.w};
            const float bf[8] = {blo.x, blo.y, blo.z, blo.w, bhi.x, bhi.y, bhi.z, bhi.w};
            #pragma unroll
            for (int i = 0; i < 8; ++i)
                #pragma unroll
                for (int j = 0; j < 8; ++j)
                    acc[i][j] += af[i] * bf[j];
        }
        pV[0] = nV[0]; pV[1] = nV[1]; pK[0] = nK[0]; pK[1] = nK[1];
    }
    __syncthreads();

    // ---- cross-wave reduction of the 64x64 context into smem[0..4095] ----
    float* red = smem;
    for (int w = 0; w < 4; ++w) {
        if (wave == w) {
            #pragma unroll
            for (int i = 0; i < 8; ++i) {
                const int base = (d0 + i) * DHH + e0;
                float4 lo = make_float4(acc[i][0], acc[i][1], acc[i][2], acc[i][3]);
                float4 hi = make_float4(acc[i][4], acc[i][5], acc[i][6], acc[i][7]);
                if (w != 0) {
                    const float4 plo = *(const float4*)&red[base];
                    const float4 phi = *(const float4*)&red[base + 4];
                    lo.x += plo.x; lo.y += plo.y; lo.z += plo.z; lo.w += plo.w;
                    hi.x += phi.x; hi.y += phi.y; hi.z += phi.z; hi.w += phi.w;
                }
                *(float4*)&red[base]     = lo;
                *(float4*)&red[base + 4] = hi;
            }
        }
        __syncthreads();
    }

    // ---- write partial context (4096 floats, 16 per thread) ----
    float* pbase = partials + (size_t)(bh * SPLITA + sp) * CTXSZ;
    #pragma unroll
    for (int i = 0; i < 4; ++i) {
        const int idx = t * 16 + i * 4;
        *(float4*)(pbase + idx) = *(const float4*)&red[idx];
    }
    // ---- reduce v2_sum across threads (reuse smem as scratch) ----
    __syncthreads();
    *(float4*)&smem[t * 4] = v2sum4;
    __syncthreads();
    if (t < DHH) {
        const int cc = t >> 2, j = t & 3;
        float s = 0.f;
        #pragma unroll
        for (int q = 0; q < 16; ++q) s += smem[(q * 16 + cc) * 4 + j];
        pbase[4096 + t] = s;
    }
}

// ---------------- Reduce partials across SPLITA (1024 blocks) ----------------
#define RSEG 16   // CTXSZ / RSEG = 260 elements per block
__global__ __launch_bounds__(256) void reduceCtx(
        const float* __restrict__ partials, float* __restrict__ ctxsum) {
    const int bh  = blockIdx.x / RSEG;
    const int seg = blockIdx.x % RSEG;
    const int t = threadIdx.x;
    const int base = seg * 260;
    for (int i = t; i < 260; i += 256) {
        const int idx = base + i;
        const float* p = partials + (size_t)bh * SPLITA * CTXSZ + idx;
        float s = 0.f;
        #pragma unroll
        for (int sp = 0; sp < SPLITA; ++sp) s += p[(size_t)sp * CTXSZ];
        ctxsum[(size_t)bh * CTXSZ + idx] = s;
    }
}

// ---------------- Phase B: X = D_inv * v1 @ context, project/mobius/project ----------------
// Wave-private 64-row tiles (no barriers after ctx preload). v1 staged TRANSPOSED
// (v1T[d][n], two 32-d halves) with XOR swizzle col^= (d & ~3) -> conflict-free
// scatter writes and b128 reads. GEMM = outer product over d: 4 ds_read_b128 per
// 64 FMAs per lane (0.0625 DS/FMA). Mobius half-angle in closed form.
__global__ __launch_bounds__(256) void phaseB(
        const float* __restrict__ Qp, const float* __restrict__ curvp,
        const float* __restrict__ denomWs, const float* __restrict__ ctxsum,
        float* __restrict__ outp) {
    __shared__ __align__(16) float ctx[DHH * DHH];      // 16 KB, plain [64][64]
    __shared__ __align__(16) float v2sum_l[DHH];
    __shared__ __align__(16) float v1T[4][32 * 64];     // 32 KB (per-wave half-tiles)
    __shared__ float dnW[4][64];                        // 1 KB

    const int bx = blockIdx.x;
    const int bh = bx / SPLITB, sp = bx % SPLITB;
    const float k = curvp[bh % HCOUNT];
    const float sk = sqrtf(fabsf(k) + 1e-15f);
    const float maxnorm = (k < 0.0f) ? (1.0f - PROJ_EPS) / sk : 1e15f;
    const int t = threadIdx.x;
    const int wave = t >> 6;
    const int lane = t & 63;

    // ---- preload ctx + v2_sum (coalesced) ----
    const float* cb = ctxsum + (size_t)bh * CTXSZ;
    #pragma unroll
    for (int i = 0; i < 16; ++i) {
        const int idx = i * 256 + t;
        ctx[idx] = cb[idx];
    }
    if (t < DHH) v2sum_l[t] = cb[4096 + t];
    __syncthreads();

    const float* Qb  = Qp   + (size_t)bh * NROWS * DHH;
    float*       Ob  = outp + (size_t)bh * NROWS * DHH;
    const float* dvb = denomWs + (size_t)bh * NROWS;

    const int r8 = lane >> 3;        // 0..7
    const int c8 = lane & 7;         // 0..7
    const int a0 = r8 * 8;           // output row block (n)
    const int e0 = c8 * 8;           // output col block (e)
    const int n0 = sp * CHUNKB + wave * 64;   // this wave's 64 rows
    float* vT  = &v1T[wave][0];
    float* dnw = &dnW[wave][0];
    const int wcolbase = 4 * c8;     // swizzle for writes: col = n ^ (4*c8)

    float acc[8][8];
    #pragma unroll
    for (int i = 0; i < 8; ++i)
        #pragma unroll
        for (int j = 0; j < 8; ++j) acc[i][j] = 0.f;

    #pragma unroll
    for (int h = 0; h < 2; ++h) {
        // ---- stage half h: v1T[d in h*32..h*32+31][n], Dn partials ----
        const float4 vs4 = *(const float4*)&v2sum_l[h * 32 + 4 * c8];
        #pragma unroll
        for (int p = 0; p < 8; ++p) {
            const int n = p * 8 + r8;
            const float4 q4 = *(const float4*)(Qb + (size_t)(n0 + n) * DHH + h * 32 + 4 * c8);
            const float idv = 1.0f / dvb[n0 + n];
            float4 v14;
            v14.x = elu1(q4.x * idv);
            v14.y = elu1(q4.y * idv);
            v14.z = elu1(q4.z * idv);
            v14.w = elu1(q4.w * idv);
            const int wcol = n ^ wcolbase;
            vT[(4 * c8 + 0) * 64 + wcol] = v14.x;
            vT[(4 * c8 + 1) * 64 + wcol] = v14.y;
            vT[(4 * c8 + 2) * 64 + wcol] = v14.z;
            vT[(4 * c8 + 3) * 64 + wcol] = v14.w;
            float dnp = v14.x * vs4.x + v14.y * vs4.y + v14.z * vs4.z + v14.w * vs4.w;
            dnp += __shfl_xor(dnp, 1);
            dnp += __shfl_xor(dnp, 2);
            dnp += __shfl_xor(dnp, 4);
            if (c8 == 0) {
                if (h == 0) dnw[n] = dnp;
                else        dnw[n] += dnp;
            }
        }
        // ---- GEMM over this half's 32 d values (wave-private, no barrier) ----
        const float* ctxh = &ctx[h * 32 * 64];
        #pragma unroll 1
        for (int dd4 = 0; dd4 < 32; dd4 += 4) {
            // swizzle s(d) = d & ~3 == dd4 within this block of 4
            const int vb1 = dd4 * 64 + (a0 ^ dd4);
            const int vb2 = dd4 * 64 + ((a0 + 4) ^ dd4);
            #pragma unroll
            for (int q = 0; q < 4; ++q) {
                const float4 alo = *(const float4*)&vT[vb1 + q * 64];
                const float4 ahi = *(const float4*)&vT[vb2 + q * 64];
                const float4 blo = *(const float4*)&ctxh[(dd4 + q) * 64 + e0];
                const float4 bhi = *(const float4*)&ctxh[(dd4 + q) * 64 + e0 + 4];
                const float af[8] = {alo.x, alo.y, alo.z, alo.w, ahi.x, ahi.y, ahi.z, ahi.w};
                const float bf[8] = {blo.x, blo.y, blo.z, blo.w, bhi.x, bhi.y, bhi.z, bhi.w};
                #pragma unroll
                for (int i = 0; i < 8; ++i)
                    #pragma unroll
                    for (int j = 0; j < 8; ++j)
                        acc[i][j] += af[i] * bf[j];
            }
        }
    }

    // ---- epilogue: D_inv, norm, project -> mobius(0.5) -> project, store ----
    #pragma unroll
    for (int i = 0; i < 8; ++i) {
        float dn = dnw[a0 + i];
        dn = (dn == 0.0f) ? EPS_DN : dn;
        const float di = 1.0f / dn;
        #pragma unroll
        for (int j = 0; j < 8; ++j) acc[i][j] *= di;
        float ss = acc[i][0]*acc[i][0] + acc[i][1]*acc[i][1] + acc[i][2]*acc[i][2] + acc[i][3]*acc[i][3]
                 + acc[i][4]*acc[i][4] + acc[i][5]*acc[i][5] + acc[i][6]*acc[i][6] + acc[i][7]*acc[i][7];
        ss += __shfl_xor(ss, 1);
        ss += __shfl_xor(ss, 2);
        ss += __shfl_xor(ss, 4);   // full row sumsq (reduced over e-groups)
        const float norm = fmaxf(sqrtf(ss), 1e-15f);
        const float f1 = (norm > maxnorm) ? (maxnorm / norm) : 1.0f;
        const float xnorm = fmaxf(norm * f1, 1e-15f);
        const float su = sk * xnorm;
        float tk;
        if (k < 0.0f) {
            const float suc = fminf(su, 1.0f - 1e-7f);
            tk = suc / (1.0f + sqrtf(fmaxf(1.0f - suc * suc, 0.0f)));   // tanh(atanh/2)
        } else {
            tk = su / (1.0f + sqrtf(1.0f + su * su));                   // tan(atan/2)
        }
        tk /= sk;
        const float f2 = tk / xnorm;
        const float n3 = fmaxf(fabsf(tk), 1e-15f);
        const float f3 = (n3 > maxnorm) ? (maxnorm / n3) : 1.0f;
        const float fac = f1 * f2 * f3;
        float4 o1 = make_float4(acc[i][0]*fac, acc[i][1]*fac, acc[i][2]*fac, acc[i][3]*fac);
        float4 o2 = make_float4(acc[i][4]*fac, acc[i][5]*fac, acc[i][6]*fac, acc[i][7]*fac);
        float* orow = Ob + (size_t)(n0 + a0 + i) * DHH + e0;
        *(float4*)orow       = o1;
        *(float4*)(orow + 4) = o2;
    }
}

extern "C" void kernel_launch(void* const* d_in, const int* in_sizes, int n_in,
                              void* d_out, int out_size, void* d_ws, size_t ws_size,
                              hipStream_t stream) {
    const float* Q    = (const float*)d_in[0];
    const float* K    = (const float*)d_in[1];
    const float* V    = (const float*)d_in[2];
    const float* mask = (const float*)d_in[3];
    const float* curv = (const float*)d_in[4];
    float* out = (float*)d_out;

    float* denomWs  = (float*)d_ws;                                   // 64*8192 floats
    float* partials = denomWs + (size_t)BHCOUNT * NROWS;              // 64*16*4160 floats
    float* ctxsum   = partials + (size_t)BHCOUNT * SPLITA * CTXSZ;    // 64*4160 floats

    phaseA<<<dim3(BHCOUNT * SPLITA), dim3(256), 0, stream>>>(K, V, mask, curv, denomWs, partials);
    reduceCtx<<<dim3(BHCOUNT * RSEG), dim3(256), 0, stream>>>(partials, ctxsum);
    phaseB<<<dim3(BHCOUNT * SPLITB), dim3(256), 0, stream>>>(Q, curv, denomWs, ctxsum, out);
}